// Round 3
// baseline (951.257 us; speedup 1.0000x reference)
//
#include <hip/hip_runtime.h>
#include <stdint.h>

// Problem constants
#define TT   300          // timesteps
#define NWG  64           // scan workgroups: 32 for layer0, 32 for layer1

// ws layout (in floats)
#define XW0_OFF   0
#define XW0_SZ    (TT*4*1024)
#define HP0_OFF   (XW0_OFF + XW0_SZ)
#define HP_SZ     (TT*1024*2)            // {h,tag} pairs: TT*1024 pairs
#define HP1_OFF   (HP0_OFF + HP_SZ)
#define HP_BYTES  ((size_t)HP_SZ * 2 * 4) // zero BOTH hp0+hp1 (adjacent)

__device__ __forceinline__ float sigf(float x){ return 1.0f/(1.0f + __expf(-x)); }
__device__ __forceinline__ float tahf(float x){ return 1.0f - 2.0f/(__expf(2.0f*x)+1.0f); }

// LLC-coherent raw loads (bypass L1+L2; no cache invalidates)
__device__ __forceinline__ uint4 llc_load16(const float* p) {
  uint4 v;
  asm volatile("global_load_dwordx4 %0, %1, off sc0 sc1\n\t"
               "s_waitcnt vmcnt(0)"
               : "=v"(v) : "v"(p) : "memory");
  return v;
}
__device__ __forceinline__ void llc_load32(const float* p, uint4& a, uint4& b) {
  asm volatile("global_load_dwordx4 %0, %2, off sc0 sc1\n\t"
               "global_load_dwordx4 %1, %2, off offset:16 sc0 sc1\n\t"
               "s_waitcnt vmcnt(0)"
               : "=&v"(a), "=&v"(b) : "v"(p) : "memory");
}
// packed {h, tag} single 8B store -> data+flag visible atomically
__device__ __forceinline__ void llc_store_pair(float* p, float h, unsigned tag) {
  union { struct { float h; unsigned t; } s; unsigned long long u; } pk;
  pk.s.h = h; pk.s.t = tag;
  __hip_atomic_store((unsigned long long*)p, pk.u,
                     __ATOMIC_RELAXED, __HIP_MEMORY_SCOPE_AGENT);
}

// ---------------- embedding gather + layer0 input projection --------------
__global__ void emb_proj_k(const float* __restrict__ enc, const int* __restrict__ inp,
                           const float* __restrict__ Wih0, const float* __restrict__ bih0,
                           const float* __restrict__ bhh0, float* __restrict__ xw0)
{
  __shared__ float xl[100];
  const int t = blockIdx.x;
  const int tid = threadIdx.x;
  if (tid < 100) {
    int q = t*100 + tid;          // flat index into emb buffer
    int s = q / 1200;
    int rm = q - s*1200;
    int bb = rm / 300;
    int e  = rm - bb*300;
    int tok = inp[bb*25 + s];
    xl[tid] = enc[(long)tok*300 + e];
  }
  __syncthreads();
  for (int rr = 0; rr < 4; ++rr) {
    int row = rr*256 + tid;
    const float* wr = Wih0 + row*25;
    float bias = bih0[row] + bhh0[row];
    float a0 = bias, a1 = bias, a2 = bias, a3 = bias;
#pragma unroll
    for (int i = 0; i < 25; ++i) {
      float w = wr[i];
      a0 += w * xl[i];
      a1 += w * xl[25+i];
      a2 += w * xl[50+i];
      a3 += w * xl[75+i];
    }
    xw0[(t*4+0)*1024 + row] = a0;
    xw0[(t*4+1)*1024 + row] = a1;
    xw0[(t*4+2)*1024 + row] = a2;
    xw0[(t*4+3)*1024 + row] = a3;
  }
}

// ---------------- persistent pipelined 2-layer LSTM scan -------------------
// WG 0..31  : layer0, units j in [wg*8, wg*8+8)       (wave = unit)
// WG 32..63 : layer1, units j in [(wg-32)*8, +8)      (wave = unit)
// Per wave: lane = g*16 + c  (gate g=0..3, k-chunk c=0..15).
// L0: chunk = 16 k ; L1: chunk = 32 k (k=512 = concat(y0, h1)).
// Weights in VGPRs (rotation-stored so LDS dot reads are bank-staggered).
// One __syncthreads per step; double-buffered hst kills the WAR barrier.
// Reduction + gate combine entirely in-wave (shfl butterfly + bpermute).
__global__ __launch_bounds__(512) void scan_k(
    const float* __restrict__ Whh0, const float* __restrict__ Wih1,
    const float* __restrict__ Whh1, const float* __restrict__ bih1,
    const float* __restrict__ bhh1, const float* __restrict__ h0in,
    const float* __restrict__ c0in, const float* __restrict__ xw0,
    float* __restrict__ hp0, float* __restrict__ hp1,
    float* __restrict__ dout)
{
  const int wg   = blockIdx.x;
  const int tid  = threadIdx.x;
  const int layer = (wg < 32) ? 0 : 1;
  const int wave = tid >> 6;
  const int lane = tid & 63;
  const int g    = lane >> 4;        // gate 0..3 (i,f,g,o)
  const int c    = lane & 15;        // k-chunk
  const int bb   = lane & 3;         // batch this lane finalizes

  __shared__ float4 hst[2][512];     // [k][b] staging, double-buffered

  float w_[32];                      // L0 uses 16
  int j;                             // global unit index
  float bl = 0.f;                    // L1: row bias (bih1+bhh1) for gate g
  float cprev;                       // cell state for (unit j, batch bb)

  if (layer == 0) {
    j = wg*8 + wave;
    int row = g*256 + j;
    const float* wr = Whh0 + row*256 + c*16;
#pragma unroll
    for (int m = 0; m < 16; ++m) w_[m] = wr[(m + c) & 15];   // rotation-stored
    cprev = c0in[bb*256 + j];
  } else {
    j = (wg-32)*8 + wave;
    int row = g*256 + j;
    const float* wr = (c < 8) ? (Wih1 + row*256 + c*32)
                              : (Whh1 + row*256 + (c-8)*32);
#pragma unroll
    for (int m = 0; m < 32; ++m) w_[m] = wr[(m + 2*c) & 31]; // rotation-stored
    bl = bih1[row] + bhh1[row];
    cprev = c0in[1024 + bb*256 + j];
  }

  const int ssBeg = layer ? 1 : 0;
  const int ssEnd = layer ? TT : (TT-1);
  int buf = 0;

  for (int ss = ssBeg; ss <= ssEnd; ++ss, buf ^= 1) {
    const int t = layer ? (ss-1) : ss;

    // ---- per-lane gate-input prefetch (L0; latency hides under poll)
    float xwv = 0.f;
    if (layer == 0)
      xwv = xw0[(size_t)(t*4 + bb)*1024 + g*256 + j];

    // ---- stage h into LDS, polling fused {h,tag} pairs
    if (layer == 0) {
      int k = tid >> 1, half = tid & 1;       // pairs 2tid, 2tid+1
      float2 v;
      if (t > 0) {
        const float* pp = hp0 + ((size_t)(t-1)*1024 + (size_t)tid*2)*2;
        const unsigned tg = (unsigned)t;
        unsigned guard = 0; uint4 q;
        do { q = llc_load16(pp); }
        while ((q.y != tg || q.w != tg) && ++guard < (1u<<20));
        v.x = __uint_as_float(q.x); v.y = __uint_as_float(q.z);
      } else {
        v.x = h0in[(half*2+0)*256 + k];
        v.y = h0in[(half*2+1)*256 + k];
      }
      *(float2*)((float*)&hst[buf][k] + half*2) = v;
    } else {
      int k = tid;                            // 4 pairs per thread
      float4 v;
      if (k < 256) {                          // y0[t] from hp0[t]
        const float* pp = hp0 + ((size_t)t*1024 + (size_t)k*4)*2;
        const unsigned tg = (unsigned)(t+1);
        unsigned guard = 0; uint4 q1, q2;
        do { llc_load32(pp, q1, q2); }
        while ((q1.y != tg || q1.w != tg || q2.y != tg || q2.w != tg) &&
               ++guard < (1u<<20));
        v.x = __uint_as_float(q1.x); v.y = __uint_as_float(q1.z);
        v.z = __uint_as_float(q2.x); v.w = __uint_as_float(q2.z);
      } else {
        int k2 = k - 256;                     // h1[t-1]
        if (t > 0) {
          const float* pp = hp1 + ((size_t)(t-1)*1024 + (size_t)k2*4)*2;
          const unsigned tg = (unsigned)t;
          unsigned guard = 0; uint4 q1, q2;
          do { llc_load32(pp, q1, q2); }
          while ((q1.y != tg || q1.w != tg || q2.y != tg || q2.w != tg) &&
                 ++guard < (1u<<20));
          v.x = __uint_as_float(q1.x); v.y = __uint_as_float(q1.z);
          v.z = __uint_as_float(q2.x); v.w = __uint_as_float(q2.z);
        } else {
          v.x = h0in[1024 + 0*256 + k2];
          v.y = h0in[1024 + 1*256 + k2];
          v.z = h0in[1024 + 2*256 + k2];
          v.w = h0in[1024 + 3*256 + k2];
        }
      }
      hst[buf][k] = v;
    }
    __syncthreads();                          // only barrier in the step

    // ---- dot: acc[b] = sum over this lane's k-chunk (bank-staggered reads)
    float4 acc; acc.x = 0.f; acc.y = 0.f; acc.z = 0.f; acc.w = 0.f;
    if (layer == 0) {
#pragma unroll
      for (int m = 0; m < 16; ++m) {
        float4 hv = hst[buf][c*16 + ((m + c) & 15)];
        float w = w_[m];
        acc.x += w*hv.x; acc.y += w*hv.y; acc.z += w*hv.z; acc.w += w*hv.w;
      }
    } else {
#pragma unroll
      for (int m = 0; m < 32; ++m) {
        float4 hv = hst[buf][c*32 + ((m + 2*c) & 31)];
        float w = w_[m];
        acc.x += w*hv.x; acc.y += w*hv.y; acc.z += w*hv.z; acc.w += w*hv.w;
      }
    }

    // ---- in-wave reduction over chunks (lane bits 0..3)
#pragma unroll
    for (int st = 1; st <= 8; st <<= 1) {
      acc.x += __shfl_xor(acc.x, st);
      acc.y += __shfl_xor(acc.y, st);
      acc.z += __shfl_xor(acc.z, st);
      acc.w += __shfl_xor(acc.w, st);
    }

    // ---- gate combine, fully in-wave (every lane computes its batch bb)
    float s = (bb==0) ? acc.x : (bb==1) ? acc.y : (bb==2) ? acc.z : acc.w;
    s += (layer == 0) ? xwv : bl;             // per-(gate,b) input proj / bias
    float gi = __shfl(s, bb);                 // gate i from lanes  0..3
    float gf = __shfl(s, 16 + bb);            // gate f from lanes 16..19
    float gg = __shfl(s, 32 + bb);            // gate g from lanes 32..35
    float go = __shfl(s, 48 + bb);            // gate o from lanes 48..51
    float cn = sigf(gf)*cprev + sigf(gi)*tahf(gg);
    float hn = sigf(go)*tahf(cn);
    cprev = cn;

    if (lane < 4) {                           // one store per (unit, batch)
      float* hp = layer ? hp1 : hp0;
      llc_store_pair(hp + ((size_t)t*1024 + j*4 + bb)*2, hn, (unsigned)(t+1));
      if (t == TT-1) {
        int off = 400000 + layer*1024;
        dout[off + bb*256 + j] = hn;          // h_stack
        dout[off + 2048 + bb*256 + j] = cn;   // c_stack
      }
    }
  }
}

// ---------------- fc + relu + vocab decode --------------------------------
__global__ void decode_k(const float* __restrict__ y1p, const float* __restrict__ fcW,
                         const float* __restrict__ fcb, const float* __restrict__ decW,
                         const float* __restrict__ decb, float* __restrict__ dout)
{
  __shared__ float y1[1024];   // [j][b]
  __shared__ float o10[40];    // [kk][b]
  const int tid = threadIdx.x;
#pragma unroll
  for (int b = 0; b < 4; ++b)
    y1[tid*4 + b] = y1p[(size_t)(tid*4 + b)*2];   // strip tags
  __syncthreads();
  if (tid < 40) {
    int kk = tid >> 2, b = tid & 3;
    float a = fcb[kk];
    for (int j = 0; j < 256; ++j) a += fcW[kk*256 + j] * y1[j*4 + b];
    o10[kk*4 + b] = fmaxf(a, 0.f);
  }
  __syncthreads();
  int v = blockIdx.x*256 + tid;
  if (v < 100000) {
    const float* dr = decW + (size_t)v*10;
    float bias = decb[v];
    float a0 = bias, a1 = bias, a2 = bias, a3 = bias;
#pragma unroll
    for (int kk = 0; kk < 10; ++kk) {
      float w = dr[kk];
      a0 += w * o10[kk*4+0];
      a1 += w * o10[kk*4+1];
      a2 += w * o10[kk*4+2];
      a3 += w * o10[kk*4+3];
    }
    float4 o; o.x = a0; o.y = a1; o.z = a2; o.w = a3;
    ((float4*)dout)[v] = o;   // decoded.T[v][0..3]
  }
}

extern "C" void kernel_launch(void* const* d_in, const int* in_sizes, int n_in,
                              void* d_out, int out_size, void* d_ws, size_t ws_size,
                              hipStream_t stream)
{
  const float* enc  = (const float*)d_in[0];
  const float* h0in = (const float*)d_in[1];
  const float* c0in = (const float*)d_in[2];
  const float* Wih0 = (const float*)d_in[3];
  const float* Whh0 = (const float*)d_in[4];
  const float* bih0 = (const float*)d_in[5];
  const float* bhh0 = (const float*)d_in[6];
  const float* Wih1 = (const float*)d_in[7];
  const float* Whh1 = (const float*)d_in[8];
  const float* bih1 = (const float*)d_in[9];
  const float* bhh1 = (const float*)d_in[10];
  const float* fcW  = (const float*)d_in[11];
  const float* fcb  = (const float*)d_in[12];
  const float* decW = (const float*)d_in[13];
  const float* decb = (const float*)d_in[14];
  const int*   inp  = (const int*)d_in[15];

  float* ws   = (float*)d_ws;
  float* xw0  = ws + XW0_OFF;
  float* hp0  = ws + HP0_OFF;
  float* hp1  = ws + HP1_OFF;
  float* dout = (float*)d_out;

  // zero all tags (valid tags >= 1) -> replay-safe
  hipMemsetAsync(hp0, 0, HP_BYTES, stream);
  emb_proj_k<<<TT, 256, 0, stream>>>(enc, inp, Wih0, bih0, bhh0, xw0);
  scan_k<<<NWG, 512, 0, stream>>>(Whh0, Wih1, Whh1, bih1, bhh1,
                                  h0in, c0in, xw0, hp0, hp1, dout);
  decode_k<<<(100000 + 255)/256, 256, 0, stream>>>(hp1 + (size_t)(TT-1)*1024*2,
                                                   fcW, fcb, decW, decb, dout);
}

// Round 4
// 690.388 us; speedup vs baseline: 1.3779x; 1.3779x over previous
//
#include <hip/hip_runtime.h>
#include <stdint.h>

// Problem constants
#define TT   300          // timesteps
#define NWG  96           // scan workgroups: 32 for layer0, 64 for layer1

// ws layout (in floats)
#define XW0_OFF   0
#define XW0_SZ    (TT*4*1024)
#define HP0_OFF   (XW0_OFF + XW0_SZ)
#define HP_SZ     (TT*1024*2)            // {h,tag} pairs
#define HP1_OFF   (HP0_OFF + HP_SZ)
#define HP_BYTES  ((size_t)HP_SZ * 2 * 4) // zero hp0+hp1 (adjacent)

#define SLOT(k) ((k) + ((k)>>3))         // measured-conflict-free pad (R2)

__device__ __forceinline__ float sigf(float x){ return 1.0f/(1.0f + __expf(-x)); }
__device__ __forceinline__ float tahf(float x){ return 1.0f - 2.0f/(__expf(2.0f*x)+1.0f); }

// LLC-coherent raw loads (bypass L1+L2; no cache invalidates)
__device__ __forceinline__ uint4 llc_load16(const float* p) {
  uint4 v;
  asm volatile("global_load_dwordx4 %0, %1, off sc0 sc1\n\t"
               "s_waitcnt vmcnt(0)"
               : "=v"(v) : "v"(p) : "memory");
  return v;
}
__device__ __forceinline__ void llc_load32(const float* p, uint4& a, uint4& b) {
  asm volatile("global_load_dwordx4 %0, %2, off sc0 sc1\n\t"
               "global_load_dwordx4 %1, %2, off offset:16 sc0 sc1\n\t"
               "s_waitcnt vmcnt(0)"
               : "=&v"(a), "=&v"(b) : "v"(p) : "memory");
}
// packed {h, tag} single 8B store -> data+flag visible atomically
__device__ __forceinline__ void llc_store_pair(float* p, float h, unsigned tag) {
  union { struct { float h; unsigned t; } s; unsigned long long u; } pk;
  pk.s.h = h; pk.s.t = tag;
  __hip_atomic_store((unsigned long long*)p, pk.u,
                     __ATOMIC_RELAXED, __HIP_MEMORY_SCOPE_AGENT);
}

#define BFLY4(A, S) { A.x += __shfl_xor(A.x, S); A.y += __shfl_xor(A.y, S); \
                      A.z += __shfl_xor(A.z, S); A.w += __shfl_xor(A.w, S); }

// ---------------- embedding gather + layer0 input projection --------------
__global__ void emb_proj_k(const float* __restrict__ enc, const int* __restrict__ inp,
                           const float* __restrict__ Wih0, const float* __restrict__ bih0,
                           const float* __restrict__ bhh0, float* __restrict__ xw0)
{
  __shared__ float xl[100];
  const int t = blockIdx.x;
  const int tid = threadIdx.x;
  if (tid < 100) {
    int q = t*100 + tid;
    int s = q / 1200;
    int rm = q - s*1200;
    int bb = rm / 300;
    int e  = rm - bb*300;
    int tok = inp[bb*25 + s];
    xl[tid] = enc[(long)tok*300 + e];
  }
  __syncthreads();
  for (int rr = 0; rr < 4; ++rr) {
    int row = rr*256 + tid;
    const float* wr = Wih0 + row*25;
    float bias = bih0[row] + bhh0[row];
    float a0 = bias, a1 = bias, a2 = bias, a3 = bias;
#pragma unroll
    for (int i = 0; i < 25; ++i) {
      float w = wr[i];
      a0 += w * xl[i];
      a1 += w * xl[25+i];
      a2 += w * xl[50+i];
      a3 += w * xl[75+i];
    }
    xw0[(t*4+0)*1024 + row] = a0;
    xw0[(t*4+1)*1024 + row] = a1;
    xw0[(t*4+2)*1024 + row] = a2;
    xw0[(t*4+3)*1024 + row] = a3;
  }
}

// ---------------- persistent pipelined 2-layer LSTM scan -------------------
// WG 0..31  : layer0, units j in [wg*8, +8)          k=256
// WG 32..95 : layer1, units j in [(wg-32)*4, +4)     k=512 = concat(y0,h1)
// Gate-sharing dot: thread = (unit u, gate-pair g2, chunk c of 8 k).
//   Each LDS float4 read feeds 2 gate rows -> 64KB/WG/step (was 128KB).
// L0: u=tid>>6, g2=(tid>>5)&1, c=tid&31.  L1: rp=tid>>6 (=u*2+g2), c=tid&63.
// Reduce: 2(L0)/3(L1)-stage shfl butterfly -> 8 partials/row -> parts LDS
//   (layout p*33+row: combine reads hit 32 distinct banks) -> 32/16-thread
//   combine with cell state in registers.  Two barriers per step.
__global__ __launch_bounds__(512) void scan_k(
    const float* __restrict__ Whh0, const float* __restrict__ Wih1,
    const float* __restrict__ Whh1, const float* __restrict__ bih1,
    const float* __restrict__ bhh1, const float* __restrict__ h0in,
    const float* __restrict__ c0in, const float* __restrict__ xw0,
    float* __restrict__ hp0, float* __restrict__ hp1,
    float* __restrict__ dout)
{
  const int wg  = blockIdx.x;
  const int tid = threadIdx.x;
  const int layer = (wg < 32) ? 0 : 1;

  __shared__ float4 hst[2][576];            // staging, double-buffered, padded
  __shared__ float4 parts[8*33 + 32];       // [p][row] at p*33+row

  float w_[2][8];                           // 2 gate rows x 8 k
  float cprev = 0.f;                        // combine-thread cell state (reg)
  float bias_g0=0.f, bias_g1=0.f, bias_g2=0.f, bias_g3=0.f;  // L1 combine

  if (layer == 0) {
    int u = tid >> 6, g2 = (tid >> 5) & 1, c = tid & 31;
    int jloc = wg*8 + u;
#pragma unroll
    for (int q = 0; q < 2; ++q) {
      const float* wr = Whh0 + ((g2 + 2*q)*256 + jloc)*256 + c*8;
#pragma unroll
      for (int m = 0; m < 8; ++m) w_[q][m] = wr[m];
    }
    if (tid < 32)                          // combine thread (u=tid>>2,b=tid&3)
      cprev = c0in[(tid&3)*256 + wg*8 + (tid>>2)];
  } else {
    int rp = tid >> 6, c = tid & 63;
    int u = rp >> 1, g2 = rp & 1;
    int jloc = (wg-32)*4 + u;
#pragma unroll
    for (int q = 0; q < 2; ++q) {
      int row = (g2 + 2*q)*256 + jloc;
      const float* wr = (c < 32) ? (Wih1 + row*256 + c*8)
                                 : (Whh1 + row*256 + (c-32)*8);
#pragma unroll
      for (int m = 0; m < 8; ++m) w_[q][m] = wr[m];
    }
    if (tid < 16) {                        // combine thread (u=tid>>2,b=tid&3)
      int cj = (wg-32)*4 + (tid>>2);
      cprev = c0in[1024 + (tid&3)*256 + cj];
      bias_g0 = bih1[0*256+cj] + bhh1[0*256+cj];
      bias_g1 = bih1[1*256+cj] + bhh1[1*256+cj];
      bias_g2 = bih1[2*256+cj] + bhh1[2*256+cj];
      bias_g3 = bih1[3*256+cj] + bhh1[3*256+cj];
    }
  }

  const int ssBeg = layer ? 1 : 0;
  const int ssEnd = layer ? TT : (TT-1);
  int buf = 0;

  for (int ss = ssBeg; ss <= ssEnd; ++ss, buf ^= 1) {
    const int t = layer ? (ss-1) : ss;

    // ---- combine-thread prefetch (drains with first poll load: overlapped)
    float xwi=0.f, xwf=0.f, xwg=0.f, xwo=0.f;
    if (layer == 0 && tid < 32) {
      const float* xwb = xw0 + (size_t)(t*4 + (tid&3))*1024 + (wg*8 + (tid>>2));
      xwi = xwb[0]; xwf = xwb[256]; xwg = xwb[512]; xwo = xwb[768];
    }

    // ---- stage h into LDS, polling fused {h,tag} pairs
    if (layer == 0) {
      int k = tid >> 1, half = tid & 1;     // pairs 2tid, 2tid+1
      float2 v;
      if (t > 0) {
        const float* pp = hp0 + ((size_t)(t-1)*1024 + (size_t)tid*2)*2;
        const unsigned tg = (unsigned)t;
        unsigned guard = 0; uint4 q;
        do { q = llc_load16(pp); }
        while ((q.y != tg || q.w != tg) && ++guard < (1u<<20));
        v.x = __uint_as_float(q.x); v.y = __uint_as_float(q.z);
      } else {
        v.x = h0in[(half*2+0)*256 + k];
        v.y = h0in[(half*2+1)*256 + k];
      }
      *(float2*)((float*)&hst[buf][SLOT(k)] + half*2) = v;
    } else {
      int k = tid;                          // 4 pairs per thread
      float4 v;
      if (k < 256) {                        // y0[t] from hp0[t]
        const float* pp = hp0 + ((size_t)t*1024 + (size_t)k*4)*2;
        const unsigned tg = (unsigned)(t+1);
        unsigned guard = 0; uint4 q1, q2;
        do { llc_load32(pp, q1, q2); }
        while ((q1.y != tg || q1.w != tg || q2.y != tg || q2.w != tg) &&
               ++guard < (1u<<20));
        v.x = __uint_as_float(q1.x); v.y = __uint_as_float(q1.z);
        v.z = __uint_as_float(q2.x); v.w = __uint_as_float(q2.z);
      } else {
        int k2 = k - 256;                   // h1[t-1]
        if (t > 0) {
          const float* pp = hp1 + ((size_t)(t-1)*1024 + (size_t)k2*4)*2;
          const unsigned tg = (unsigned)t;
          unsigned guard = 0; uint4 q1, q2;
          do { llc_load32(pp, q1, q2); }
          while ((q1.y != tg || q1.w != tg || q2.y != tg || q2.w != tg) &&
                 ++guard < (1u<<20));
          v.x = __uint_as_float(q1.x); v.y = __uint_as_float(q1.z);
          v.z = __uint_as_float(q2.x); v.w = __uint_as_float(q2.z);
        } else {
          v.x = h0in[1024 + 0*256 + k2];
          v.y = h0in[1024 + 1*256 + k2];
          v.z = h0in[1024 + 2*256 + k2];
          v.w = h0in[1024 + 3*256 + k2];
        }
      }
      hst[buf][SLOT(k)] = v;
    }
    __syncthreads();                        // B1: staging complete

    // ---- dot: each float4 read feeds both gate rows of this thread
    float4 a0, a1;
    a0.x=0.f;a0.y=0.f;a0.z=0.f;a0.w=0.f;
    a1.x=0.f;a1.y=0.f;a1.z=0.f;a1.w=0.f;
    {
      int cbase = (layer == 0) ? ((tid & 31)*8) : ((tid & 63)*8);
#pragma unroll
      for (int m = 0; m < 8; ++m) {
        float4 hv = hst[buf][SLOT(cbase + m)];
        float q0 = w_[0][m], q1 = w_[1][m];
        a0.x += q0*hv.x; a0.y += q0*hv.y; a0.z += q0*hv.z; a0.w += q0*hv.w;
        a1.x += q1*hv.x; a1.y += q1*hv.y; a1.z += q1*hv.z; a1.w += q1*hv.w;
      }
    }

    // ---- butterfly: reduce chunks to 8 classes per row
    BFLY4(a0, 8); BFLY4(a1, 8);
    BFLY4(a0, 16); BFLY4(a1, 16);
    if (layer == 1) { BFLY4(a0, 32); BFLY4(a1, 32); }

    // ---- parts write: [p][row], row-major with p*33 pad
    if (layer == 0) {
      if ((tid & 31) < 8) {
        int p = tid & 7, u = tid >> 6, g2 = (tid >> 5) & 1;
        parts[p*33 + (g2+0)*8 + u] = a0;
        parts[p*33 + (g2+2)*8 + u] = a1;
      }
    } else {
      if ((tid & 63) < 8) {
        int p = tid & 7, rp = tid >> 6;
        int u = rp >> 1, g2 = rp & 1;
        parts[p*33 + (g2+0)*4 + u] = a0;
        parts[p*33 + (g2+2)*4 + u] = a1;
      }
    }
    __syncthreads();                        // B2: partials ready

    // ---- combine: gate sums + cell update + {h,tag} broadcast
    const float* pf = (const float*)parts;
    if (layer == 0) {
      if (tid < 32) {
        int u = tid >> 2, b = tid & 3;
        float s0=0.f,s1=0.f,s2=0.f,s3=0.f;
#pragma unroll
        for (int p = 0; p < 8; ++p) {
          int base = (p*33 + u)*4 + b;
          s0 += pf[base];
          s1 += pf[base + 32];              // gate row +8 float4
          s2 += pf[base + 64];
          s3 += pf[base + 96];
        }
        int j = wg*8 + u;
        float gi = s0 + xwi, gf = s1 + xwf, gc = s2 + xwg, go = s3 + xwo;
        float cn = sigf(gf)*cprev + sigf(gi)*tahf(gc);
        float hn = sigf(go)*tahf(cn);
        cprev = cn;
        llc_store_pair(hp0 + ((size_t)t*1024 + j*4 + b)*2, hn, (unsigned)(t+1));
        if (t == TT-1) {
          dout[400000 + b*256 + j] = hn;
          dout[400000 + 2048 + b*256 + j] = cn;
        }
      }
    } else {
      if (tid < 16) {
        int u = tid >> 2, b = tid & 3;
        float s0=0.f,s1=0.f,s2=0.f,s3=0.f;
#pragma unroll
        for (int p = 0; p < 8; ++p) {
          int base = (p*33 + u)*4 + b;
          s0 += pf[base];
          s1 += pf[base + 16];              // gate row +4 float4
          s2 += pf[base + 32];
          s3 += pf[base + 48];
        }
        int j = (wg-32)*4 + u;
        float gi = s0 + bias_g0, gf = s1 + bias_g1;
        float gc = s2 + bias_g2, go = s3 + bias_g3;
        float cn = sigf(gf)*cprev + sigf(gi)*tahf(gc);
        float hn = sigf(go)*tahf(cn);
        cprev = cn;
        llc_store_pair(hp1 + ((size_t)t*1024 + j*4 + b)*2, hn, (unsigned)(t+1));
        if (t == TT-1) {
          dout[400000 + 1024 + b*256 + j] = hn;
          dout[400000 + 2048 + 1024 + b*256 + j] = cn;
        }
      }
    }
    // no 3rd barrier: parts reads finish before this thread reaches B1(t+1),
    // and parts writes of t+1 happen only after B1(t+1).
  }
}

// ---------------- fc + relu + vocab decode --------------------------------
__global__ void decode_k(const float* __restrict__ y1p, const float* __restrict__ fcW,
                         const float* __restrict__ fcb, const float* __restrict__ decW,
                         const float* __restrict__ decb, float* __restrict__ dout)
{
  __shared__ float y1[1024];   // [j][b]
  __shared__ float o10[40];    // [kk][b]
  const int tid = threadIdx.x;
#pragma unroll
  for (int b = 0; b < 4; ++b)
    y1[tid*4 + b] = y1p[(size_t)(tid*4 + b)*2];   // strip tags
  __syncthreads();
  if (tid < 40) {
    int kk = tid >> 2, b = tid & 3;
    float a = fcb[kk];
    for (int j = 0; j < 256; ++j) a += fcW[kk*256 + j] * y1[j*4 + b];
    o10[kk*4 + b] = fmaxf(a, 0.f);
  }
  __syncthreads();
  int v = blockIdx.x*256 + tid;
  if (v < 100000) {
    const float* dr = decW + (size_t)v*10;
    float bias = decb[v];
    float a0 = bias, a1 = bias, a2 = bias, a3 = bias;
#pragma unroll
    for (int kk = 0; kk < 10; ++kk) {
      float w = dr[kk];
      a0 += w * o10[kk*4+0];
      a1 += w * o10[kk*4+1];
      a2 += w * o10[kk*4+2];
      a3 += w * o10[kk*4+3];
    }
    float4 o; o.x = a0; o.y = a1; o.z = a2; o.w = a3;
    ((float4*)dout)[v] = o;   // decoded.T[v][0..3]
  }
}

extern "C" void kernel_launch(void* const* d_in, const int* in_sizes, int n_in,
                              void* d_out, int out_size, void* d_ws, size_t ws_size,
                              hipStream_t stream)
{
  const float* enc  = (const float*)d_in[0];
  const float* h0in = (const float*)d_in[1];
  const float* c0in = (const float*)d_in[2];
  const float* Wih0 = (const float*)d_in[3];
  const float* Whh0 = (const float*)d_in[4];
  const float* bih0 = (const float*)d_in[5];
  const float* bhh0 = (const float*)d_in[6];
  const float* Wih1 = (const float*)d_in[7];
  const float* Whh1 = (const float*)d_in[8];
  const float* bih1 = (const float*)d_in[9];
  const float* bhh1 = (const float*)d_in[10];
  const float* fcW  = (const float*)d_in[11];
  const float* fcb  = (const float*)d_in[12];
  const float* decW = (const float*)d_in[13];
  const float* decb = (const float*)d_in[14];
  const int*   inp  = (const int*)d_in[15];

  float* ws   = (float*)d_ws;
  float* xw0  = ws + XW0_OFF;
  float* hp0  = ws + HP0_OFF;
  float* hp1  = ws + HP1_OFF;
  float* dout = (float*)d_out;

  // zero all tags (valid tags >= 1) -> replay-safe
  hipMemsetAsync(hp0, 0, HP_BYTES, stream);
  emb_proj_k<<<TT, 256, 0, stream>>>(enc, inp, Wih0, bih0, bhh0, xw0);
  scan_k<<<NWG, 512, 0, stream>>>(Whh0, Wih1, Whh1, bih1, bhh1,
                                  h0in, c0in, xw0, hp0, hp1, dout);
  decode_k<<<(100000 + 255)/256, 256, 0, stream>>>(hp1 + (size_t)(TT-1)*1024*2,
                                                   fcW, fcb, decW, decb, dout);
}